// Round 10
// baseline (99.781 us; speedup 1.0000x reference)
//
#include <hip/hip_runtime.h>
#include <math.h>

// Problem constants (fixed by reference: H=256, N=64, CH=1, L=2048)
#define NH   256
#define NN   64
#define LSEQ 2048
#define SB   72      // short stride: 144 B = 36 dwords === 4 mod 32 -> b128 16-lane phases conflict-free
#define NTH  1024

typedef __attribute__((ext_vector_type(8))) short short8;     // 8 bf16 (MFMA A/B frag)
typedef __attribute__((ext_vector_type(4))) float float4_t;   // MFMA C/D frag
typedef unsigned short u16;

#define MFMA(a,b,c) __builtin_amdgcn_mfma_f32_16x16x32_bf16((a),(b),(c),0,0,0)
#define PERM_HI 0x07060302u

// fp32 -> bf16 hi (truncate) + bf16 lo (truncated remainder): 16-bit mantissa total
static __device__ __forceinline__ void split1(float v, u16& h, u16& l) {
    unsigned u = __float_as_uint(v);
    unsigned hv = u & 0xffff0000u;
    h = (u16)(u >> 16);
    l = (u16)(__float_as_uint(v - __uint_as_float(hv)) >> 16);
}
static __device__ __forceinline__ float join1(u16 h, u16 l) {
    return __uint_as_float((unsigned)h << 16) + __uint_as_float((unsigned)l << 16);
}
static __device__ __forceinline__ void st2(u16* base, int idx, u16 a, u16 b) {
    *(unsigned*)(base + idx) = (unsigned)a | ((unsigned)b << 16);   // idx even
}
// hi/lo frags from 8 fp32 bit patterns in registers (Newton m1 global path)
static __device__ __forceinline__ void frag_vals(const unsigned* e, short8& hi, short8& lo) {
    unsigned lb[8];
#pragma unroll
    for (int m = 0; m < 8; ++m) {
        unsigned hv = e[m] & 0xffff0000u;
        lb[m] = __float_as_uint(__uint_as_float(e[m]) - __uint_as_float(hv));
    }
    union { short8 s; unsigned u[4]; } H, L;
#pragma unroll
    for (int m = 0; m < 4; ++m) {
        H.u[m] = __builtin_amdgcn_perm(e[2*m+1],  e[2*m],  PERM_HI);
        L.u[m] = __builtin_amdgcn_perm(lb[2*m+1], lb[2*m], PERM_HI);
    }
    hi = H.s; lo = L.s;
}
static __device__ __forceinline__ short8 neg8(short8 v) {
    union { short8 s; int i[4]; } u; u.s = v;
#pragma unroll
    for (int m = 0; m < 4; ++m) u.i[m] ^= 0x80008000;
    return u.s;
}

// One 16x16 tile of complex P = A*B, K=64. A/B sets are pre-split hi/lo bf16
// arrays; A read as rows [arow*SB+k..], B as rows of its TRANSPOSE set
// [bcol*SB+k..]. Frag load = 2 ds_read_b128, zero VALU.
template<bool IMAG>
static __device__ __forceinline__ void cmm_tile(
    const u16* Arh, const u16* Arl, const u16* Aih, const u16* Ail,
    const u16* Brh, const u16* Brl, const u16* Bih, const u16* Bil,
    int arow, int bcol, int fq, float4_t& accR, float4_t& accI)
{
#pragma unroll
    for (int ks = 0; ks < 2; ++ks) {
        const int k0 = ks*32 + fq*8;
        const int ao = arow*SB + k0, bo = bcol*SB + k0;
        short8 arh = *(const short8*)(Arh + ao);
        short8 arl = *(const short8*)(Arl + ao);
        short8 aih = *(const short8*)(Aih + ao);
        short8 ail = *(const short8*)(Ail + ao);
        short8 brh = *(const short8*)(Brh + bo);
        short8 brl = *(const short8*)(Brl + bo);
        short8 bih = *(const short8*)(Bih + bo);
        short8 bil = *(const short8*)(Bil + bo);
        short8 naih = neg8(aih), nail = neg8(ail);
        accR = MFMA(arh, brh, accR); accR = MFMA(arh, brl, accR); accR = MFMA(arl, brh, accR);
        accR = MFMA(naih, bih, accR); accR = MFMA(naih, bil, accR); accR = MFMA(nail, bih, accR);
        if (IMAG) {
            accI = MFMA(arh, bih, accI); accI = MFMA(arh, bil, accI); accI = MFMA(arl, bih, accI);
            accI = MFMA(aih, brh, accI); accI = MFMA(aih, brl, accI); accI = MFMA(ail, brh, accI);
        }
    }
}

// k[h, 64j+i] = Re( g_j . x_i ),  g_j = c^T (dA^64)^j,  x_i = dA^i dB
// Cubic Newton (X1 = I + (dt/2)A; Y = Ab*X1; V = X1*Y; X2 = 3X1 - 3V + VY),
// P = dA = 2*X2 - I folded into m3 epilogue. dB = dt/2 (dA b + b) chained matvec.
// Ladder: 9 squarings to dA^512; X-rounds C=2..32 ride s=2..6; G-rounds C=1,2,4
// ride s=7..9; tail: 3 chained dA^512 G-steps + direct-global K stores.
__global__ __launch_bounds__(NTH, 4) void ssm_kernel(
    const float* __restrict__ Ag,
    const float* __restrict__ Bg,
    const float* __restrict__ Cg,
    const float* __restrict__ LogDt,
    float* __restrict__ outp)
{
    __shared__ __align__(16) unsigned char lds[130048];
    u16* XRrh = (u16*)(lds +      0);   // P row-major re hi
    u16* XRrl = (u16*)(lds +   9216);
    u16* XRih = (u16*)(lds +  18432);
    u16* XRil = (u16*)(lds +  27648);
    u16* XTrh = (u16*)(lds +  36864);   // P^T re hi
    u16* XTrl = (u16*)(lds +  46080);
    u16* XTih = (u16*)(lds +  55296);
    u16* XTil = (u16*)(lds +  64512);
    u16* Xfrh = (u16*)(lds +  73728);   // x rows (also Newton Y^T)
    u16* Xfrl = (u16*)(lds +  82944);
    u16* Xfih = (u16*)(lds +  92160);
    u16* Xfil = (u16*)(lds + 101376);
    u16* Grh  = (u16*)(lds + 110592);   // g rows, 32 x SB
    u16* Grl  = (u16*)(lds + 115200);
    u16* Gih  = (u16*)(lds + 119808);
    u16* Gil  = (u16*)(lds + 124416);
    float* bvr = (float*)(lds + 129024);
    float* bvi = (float*)(lds + 129280);
    float* urr = (float*)(lds + 129536);   // u = dA*b scratch
    float* uri = (float*)(lds + 129792);

    const int t    = threadIdx.x;
    const int lane = t & 63;
    const int wv   = t >> 6;                 // 0..15
    const int ti   = wv >> 2, tj = wv & 3;
    const int fm   = lane & 15, fq = lane >> 4;
    const int h    = blockIdx.x;

    const float dt  = expf(LogDt[h]);
    const float hdt = 0.5f * dt;

    const float2* A2 = (const float2*)(Ag + (size_t)h * NN * NN * 2);
    const float4_t z4 = {0.f, 0.f, 0.f, 0.f};

    // ---- seed P = X1 = I + (dt/2)A (both views, split); load b, c ----
#pragma unroll
    for (int e = 0; e < 4; ++e) {
        int idx = t + e*NTH;
        int i = idx >> 6, j = idx & 63;
        float2 a = A2[idx];
        u16 rh, rl, ih, il;
        split1((i == j ? 1.0f : 0.0f) + hdt * a.x, rh, rl);
        split1(hdt * a.y, ih, il);
        XRrh[i*SB + j] = rh; XRrl[i*SB + j] = rl;
        XRih[i*SB + j] = ih; XRil[i*SB + j] = il;
        XTrh[j*SB + i] = rh; XTrl[j*SB + i] = rl;
        XTih[j*SB + i] = ih; XTil[j*SB + i] = il;
    }
    if (t < NN) {
        float2 bv = ((const float2*)Bg)[h*NN + t];
        float2 cv = ((const float2*)Cg)[h*NN + t];
        bvr[t] = bv.x; bvi[t] = bv.y;
        u16 hh, ll;
        split1(cv.x, hh, ll); Grh[t] = hh; Grl[t] = ll;   // g_0 = c
        split1(cv.y, hh, ll); Gih[t] = hh; Gil[t] = ll;
    }
    __syncthreads();

    const int arow = ti*16 + fm;
    const int bcol = tj*16 + fm;

    // ---- m1: Y = Ab*X1 (Ab from global, Bt = XT); write Y^T -> Xf set ----
    {
        float4_t aR = z4, aI = z4;
#pragma unroll
        for (int ks = 0; ks < 2; ++ks) {
            const int k0 = ks*32 + fq*8;
            unsigned vr[8], vi[8];
#pragma unroll
            for (int j = 0; j < 8; ++j) {
                float2 a = A2[arow*NN + k0 + j];
                vr[j] = __float_as_uint((arow == k0 + j ? 1.0f : 0.0f) - hdt * a.x);
                vi[j] = __float_as_uint(-hdt * a.y);
            }
            short8 arh, arl, aih, ail;
            frag_vals(vr, arh, arl);
            frag_vals(vi, aih, ail);
            const int bo = bcol*SB + k0;
            short8 brh = *(const short8*)(XTrh + bo);
            short8 brl = *(const short8*)(XTrl + bo);
            short8 bih = *(const short8*)(XTih + bo);
            short8 bil = *(const short8*)(XTil + bo);
            short8 naih = neg8(aih), nail = neg8(ail);
            aR = MFMA(arh, brh, aR); aR = MFMA(arh, brl, aR); aR = MFMA(arl, brh, aR);
            aR = MFMA(naih, bih, aR); aR = MFMA(naih, bil, aR); aR = MFMA(nail, bih, aR);
            aI = MFMA(arh, bih, aI); aI = MFMA(arh, bil, aI); aI = MFMA(arl, bih, aI);
            aI = MFMA(aih, brh, aI); aI = MFMA(aih, brl, aI); aI = MFMA(ail, brh, aI);
        }
        u16 hr[4], lr[4], hi_[4], li_[4];
#pragma unroll
        for (int r = 0; r < 4; ++r) { split1(aR[r], hr[r], lr[r]); split1(aI[r], hi_[r], li_[r]); }
        const int tb = bcol*SB + ti*16 + fq*4;    // Y^T rows contiguous -> b32 pairs
        st2(Xfrh, tb, hr[0], hr[1]); st2(Xfrh, tb+2, hr[2], hr[3]);
        st2(Xfrl, tb, lr[0], lr[1]); st2(Xfrl, tb+2, lr[2], lr[3]);
        st2(Xfih, tb, hi_[0], hi_[1]); st2(Xfih, tb+2, hi_[2], hi_[3]);
        st2(Xfil, tb, li_[0], li_[1]); st2(Xfil, tb+2, li_[2], li_[3]);
    }
    __syncthreads();

    // ---- m2: V = X1*Y (A = XR, Bt = Xf); overwrite XR with V ----
    {
        float4_t aR = z4, aI = z4;
        cmm_tile<true>(XRrh,XRrl,XRih,XRil, Xfrh,Xfrl,Xfih,Xfil, arow, bcol, fq, aR, aI);
        __syncthreads();
#pragma unroll
        for (int r = 0; r < 4; ++r) {
            int row = ti*16 + fq*4 + r;
            u16 hh, ll;
            split1(aR[r], hh, ll); XRrh[row*SB + bcol] = hh; XRrl[row*SB + bcol] = ll;
            split1(aI[r], hh, ll); XRih[row*SB + bcol] = hh; XRil[row*SB + bcol] = ll;
        }
    }
    __syncthreads();

    // ---- m3: P = dA = 2*(3X1 - 3V + V*Y) - I ; write both views ----
    {
        float4_t aR = z4, aI = z4;
        cmm_tile<true>(XRrh,XRrl,XRih,XRil, Xfrh,Xfrl,Xfih,Xfil, arow, bcol, fq, aR, aI);
        float p_r[4], p_i[4];
#pragma unroll
        for (int r = 0; r < 4; ++r) {           // pre-barrier elementwise reads
            int row = ti*16 + fq*4 + r;
            float2 a = A2[row*NN + bcol];
            float x1r = (row == bcol ? 1.0f : 0.0f) + hdt * a.x;
            float x1i = hdt * a.y;
            float vvr = join1(XRrh[row*SB + bcol], XRrl[row*SB + bcol]);
            float vvi = join1(XRih[row*SB + bcol], XRil[row*SB + bcol]);
            p_r[r] = 2.0f*(3.0f*x1r - 3.0f*vvr + aR[r]) - (row == bcol ? 1.0f : 0.0f);
            p_i[r] = 2.0f*(3.0f*x1i - 3.0f*vvi + aI[r]);
        }
        __syncthreads();   // all V/Y reads done
        u16 hr[4], lr[4], hi_[4], li_[4];
#pragma unroll
        for (int r = 0; r < 4; ++r) { split1(p_r[r], hr[r], lr[r]); split1(p_i[r], hi_[r], li_[r]); }
#pragma unroll
        for (int r = 0; r < 4; ++r) {
            int row = ti*16 + fq*4 + r;
            XRrh[row*SB + bcol] = hr[r]; XRrl[row*SB + bcol] = lr[r];
            XRih[row*SB + bcol] = hi_[r]; XRil[row*SB + bcol] = li_[r];
        }
        const int tb = bcol*SB + ti*16 + fq*4;
        st2(XTrh, tb, hr[0], hr[1]); st2(XTrh, tb+2, hr[2], hr[3]);
        st2(XTrl, tb, lr[0], lr[1]); st2(XTrl, tb+2, lr[2], lr[3]);
        st2(XTih, tb, hi_[0], hi_[1]); st2(XTih, tb+2, hi_[2], hi_[3]);
        st2(XTil, tb, li_[0], li_[1]); st2(XTil, tb+2, li_[2], li_[3]);
    }
    __syncthreads();
    // P = dA (both views)

    // ---- u = dA*b (phase 1 of chained dB matvec) ----
    {
        int n = t >> 4, part = t & 15;
        float ar = 0.f, ai = 0.f;
#pragma unroll
        for (int qq = 0; qq < 4; ++qq) {
            int k = part + 16*qq;
            float mr = join1(XRrh[n*SB + k], XRrl[n*SB + k]);
            float mi = join1(XRih[n*SB + k], XRil[n*SB + k]);
            ar += mr*bvr[k] - mi*bvi[k];
            ai += mr*bvi[k] + mi*bvr[k];
        }
#pragma unroll
        for (int off = 8; off; off >>= 1) { ar += __shfl_xor(ar, off); ai += __shfl_xor(ai, off); }
        if (part == 0) { urr[n] = ar; uri[n] = ai; }
    }
    __syncthreads();

    // ---- ladder s = 1..9: riders (pre-barrier) + squaring (all 16 waves) ----
    // s=1 rider: x_0 = dt/2(u+b), x_1 = dt/2(dA u + u)  (scalar, all threads)
    // s=2..6 rider: X-round C=2^(s-1): Xf[C+r] = Xf[r] . P^T  (Bt = XR)
    // s=7..9 rider: G-round C=2^(s-7): G[C+r] = G[r] . P      (Bt = XT)
    // stale A-rows produce garbage rows >= 2C only, overwritten before use.
#pragma unroll 1
    for (int s = 1; s <= 9; ++s) {
        if (s == 1) {
            int n = t >> 4, part = t & 15;
            float ar = 0.f, ai = 0.f;
#pragma unroll
            for (int qq = 0; qq < 4; ++qq) {
                int k = part + 16*qq;
                float mr = join1(XRrh[n*SB + k], XRrl[n*SB + k]);
                float mi = join1(XRih[n*SB + k], XRil[n*SB + k]);
                ar += mr*urr[k] - mi*uri[k];
                ai += mr*uri[k] + mi*urr[k];
            }
#pragma unroll
            for (int off = 8; off; off >>= 1) { ar += __shfl_xor(ar, off); ai += __shfl_xor(ai, off); }
            if (part == 0) {
                float u_r = urr[n], u_i = uri[n];
                u16 hh, ll;
                split1(hdt*(u_r + bvr[n]), hh, ll); Xfrh[n] = hh; Xfrl[n] = ll;
                split1(hdt*(u_i + bvi[n]), hh, ll); Xfih[n] = hh; Xfil[n] = ll;
                split1(hdt*(ar + u_r), hh, ll); Xfrh[SB + n] = hh; Xfrl[SB + n] = ll;
                split1(hdt*(ai + u_i), hh, ll); Xfih[SB + n] = hh; Xfil[SB + n] = ll;
            }
        } else if (s <= 6) {
            const int C = 1 << (s-1);
            const int nT = (s == 6) ? 8 : 4;
            if (wv < nT) {
                int rt = wv >> 2, ct = wv & 3;
                float4_t aR = z4, aI = z4;
                cmm_tile<true>(Xfrh,Xfrl,Xfih,Xfil, XRrh,XRrl,XRih,XRil,
                               rt*16 + fm, ct*16 + fm, fq, aR, aI);
#pragma unroll
                for (int r = 0; r < 4; ++r) {
                    int row = C + rt*16 + fq*4 + r;
                    int col = ct*16 + fm;
                    u16 hh, ll;
                    split1(aR[r], hh, ll); Xfrh[row*SB + col] = hh; Xfrl[row*SB + col] = ll;
                    split1(aI[r], hh, ll); Xfih[row*SB + col] = hh; Xfil[row*SB + col] = ll;
                }
            }
        } else {
            const int C = 1 << (s-7);     // 1,2,4
            if (wv < 4) {
                float4_t aR = z4, aI = z4;
                cmm_tile<true>(Grh,Grl,Gih,Gil, XTrh,XTrl,XTih,XTil,
                               fm, wv*16 + fm, fq, aR, aI);
#pragma unroll
                for (int r = 0; r < 4; ++r) {
                    int row = C + fq*4 + r;   // <= 19 < 32, no mask
                    int col = wv*16 + fm;
                    u16 hh, ll;
                    split1(aR[r], hh, ll); Grh[row*SB + col] = hh; Grl[row*SB + col] = ll;
                    split1(aI[r], hh, ll); Gih[row*SB + col] = hh; Gil[row*SB + col] = ll;
                }
            }
        }
        // squaring: P <- P*P
        float4_t sR = z4, sI = z4;
        cmm_tile<true>(XRrh,XRrl,XRih,XRil, XTrh,XTrl,XTih,XTil, arow, bcol, fq, sR, sI);
        __syncthreads();   // all P reads (riders + frags) complete
        u16 hr[4], lr[4], hi_[4], li_[4];
#pragma unroll
        for (int r = 0; r < 4; ++r) { split1(sR[r], hr[r], lr[r]); split1(sI[r], hi_[r], li_[r]); }
#pragma unroll
        for (int r = 0; r < 4; ++r) {
            int row = ti*16 + fq*4 + r;
            XRrh[row*SB + bcol] = hr[r]; XRrl[row*SB + bcol] = lr[r];
            XRih[row*SB + bcol] = hi_[r]; XRil[row*SB + bcol] = li_[r];
        }
        const int tb = bcol*SB + ti*16 + fq*4;
        st2(XTrh, tb, hr[0], hr[1]); st2(XTrh, tb+2, hr[2], hr[3]);
        st2(XTrl, tb, lr[0], lr[1]); st2(XTrl, tb+2, lr[2], lr[3]);
        st2(XTih, tb, hi_[0], hi_[1]); st2(XTih, tb+2, hi_[2], hi_[3]);
        st2(XTil, tb, li_[0], li_[1]); st2(XTil, tb+2, li_[2], li_[3]);
        __syncthreads();
    }
    // P = dA^512 ; Xf rows 0..63 = x_i ; G rows 0..7 = g_0..g_7

    // ---- tail tt = 0..3: chained dA^512 G-steps + K tiles (direct global) ----
#pragma unroll 1
    for (int tt = 0; tt < 4; ++tt) {
        if (tt < 3 && wv < 4) {            // G rows [8+8tt, 24+8tt) <- rows [8tt, 8tt+16)
            const int ab = tt * 8;
            float4_t aR = z4, aI = z4;
            cmm_tile<true>(Grh,Grl,Gih,Gil, XTrh,XTrl,XTih,XTil,
                           ab + fm, wv*16 + fm, fq, aR, aI);
#pragma unroll
            for (int r = 0; r < 4; ++r) {
                int row = 8 + ab + fq*4 + r;
                if (row < 32) {
                    int col = wv*16 + fm;
                    u16 hh, ll;
                    split1(aR[r], hh, ll); Grh[row*SB + col] = hh; Grl[row*SB + col] = ll;
                    split1(aI[r], hh, ll); Gih[row*SB + col] = hh; Gil[row*SB + col] = ll;
                }
            }
        }
        if (wv >= 4 && wv < 8) {           // K rows [8tt, 8tt+8): direct global store
            const int jb = tt * 8;
            float4_t aR = z4, aI = z4;
            cmm_tile<false>(Grh,Grl,Gih,Gil, Xfrh,Xfrl,Xfih,Xfil,
                            jb + fm, (wv-4)*16 + fm, fq, aR, aI);
            if (fq < 2) {
                size_t base = (size_t)h * LSEQ;
#pragma unroll
                for (int r = 0; r < 4; ++r)
                    outp[base + (jb + fq*4 + r)*NN + (wv-4)*16 + fm] = aR[r];
            }
        }
        if (tt < 3) __syncthreads();
    }
}

extern "C" void kernel_launch(void* const* d_in, const int* in_sizes, int n_in,
                              void* d_out, int out_size, void* d_ws, size_t ws_size,
                              hipStream_t stream) {
    const float* A  = (const float*)d_in[0];
    const float* B  = (const float*)d_in[1];
    const float* C  = (const float*)d_in[2];
    const float* ld = (const float*)d_in[3];
    float* out = (float*)d_out;
    ssm_kernel<<<dim3(NH), dim3(NTH), 0, stream>>>(A, B, C, ld, out);
}

// Round 11
// 96.553 us; speedup vs baseline: 1.0334x; 1.0334x over previous
//
#include <hip/hip_runtime.h>
#include <math.h>

// Problem constants (fixed by reference: H=256, N=64, CH=1, L=2048)
#define NH   256
#define NN   64
#define LSEQ 2048
#define SDW  68      // dword row stride: 68 mod 32 = 4 -> b128 phases tile 32 banks x2
#define NTH  1024

typedef __attribute__((ext_vector_type(8))) short short8;     // 8 bf16 (MFMA A/B frag)
typedef __attribute__((ext_vector_type(4))) float float4_t;   // MFMA C/D frag

#define MFMA(a,b,c) __builtin_amdgcn_mfma_f32_16x16x32_bf16((a),(b),(c),0,0,0)
#define PERM_HI 0x07060302u   // [a.hi16 | b.hi16]
#define PERM_LO 0x05040100u   // [a.lo16 | b.lo16]

// packed element: dword = [bf16hi | bf16lo], value = hi + lo (16-bit mantissa)
static __device__ __forceinline__ unsigned pack2(float v) {
    unsigned hv = __float_as_uint(v) & 0xffff0000u;
    float lo = v - __uint_as_float(hv);
    return __builtin_amdgcn_perm(hv, __float_as_uint(lo), PERM_HI);
}
static __device__ __forceinline__ float unpack2(unsigned w) {
    return __uint_as_float(w & 0xffff0000u) + __uint_as_float(w << 16);
}

static __device__ __forceinline__ void frag_vals(const unsigned* e, short8& hi, short8& lo) {
    unsigned lb[8];
#pragma unroll
    for (int m = 0; m < 8; ++m) {
        unsigned hv = e[m] & 0xffff0000u;
        lb[m] = __float_as_uint(__uint_as_float(e[m]) - __uint_as_float(hv));
    }
    union { short8 s; unsigned u[4]; } H, L;
#pragma unroll
    for (int m = 0; m < 4; ++m) {
        H.u[m] = __builtin_amdgcn_perm(e[2*m+1],  e[2*m],  PERM_HI);
        L.u[m] = __builtin_amdgcn_perm(lb[2*m+1], lb[2*m], PERM_HI);
    }
    hi = H.s; lo = L.s;
}
static __device__ __forceinline__ void frag_f32(const float* p, short8& hi, short8& lo) {
    const uint4* q = (const uint4*)p;
    uint4 d0 = q[0], d1 = q[1];
    unsigned e[8] = {d0.x, d0.y, d0.z, d0.w, d1.x, d1.y, d1.z, d1.w};
    frag_vals(e, hi, lo);
}
static __device__ __forceinline__ void frag_packed(const unsigned* p, short8& hi, short8& lo) {
    const uint4* q = (const uint4*)p;
    uint4 d0 = q[0], d1 = q[1];
    unsigned e[8] = {d0.x, d0.y, d0.z, d0.w, d1.x, d1.y, d1.z, d1.w};
    union { short8 s; unsigned u[4]; } H, L;
#pragma unroll
    for (int m = 0; m < 4; ++m) {
        H.u[m] = __builtin_amdgcn_perm(e[2*m+1], e[2*m], PERM_HI);
        L.u[m] = __builtin_amdgcn_perm(e[2*m+1], e[2*m], PERM_LO);
    }
    hi = H.s; lo = L.s;
}
static __device__ __forceinline__ short8 neg8(short8 v) {
    union { short8 s; int i[4]; } u; u.s = v;
#pragma unroll
    for (int m = 0; m < 4; ++m) u.i[m] ^= 0x80008000;
    return u.s;
}

// One 16x16 tile of complex P = A*B, K=64. A read as rows [arow*SDW+k..];
// B read as rows of the B-TRANSPOSE array [bcol*SDW+k..] (both b128-clean).
template<bool AP, bool BP, bool IMAG>
static __device__ __forceinline__ void cmm_tile(
    const void* Ar_, const void* Ai_, const void* Br_, const void* Bi_,
    int arow, int bcol, int fq, float4_t& accR, float4_t& accI)
{
#pragma unroll
    for (int ks = 0; ks < 2; ++ks) {
        const int k0 = ks*32 + fq*8;
        short8 Arh, Arl, Aih, Ail, Brh, Brl, Bih, Bil;
        if (AP) {
            frag_packed((const unsigned*)Ar_ + arow*SDW + k0, Arh, Arl);
            frag_packed((const unsigned*)Ai_ + arow*SDW + k0, Aih, Ail);
        } else {
            frag_f32((const float*)Ar_ + arow*SDW + k0, Arh, Arl);
            frag_f32((const float*)Ai_ + arow*SDW + k0, Aih, Ail);
        }
        if (BP) {
            frag_packed((const unsigned*)Br_ + bcol*SDW + k0, Brh, Brl);
            frag_packed((const unsigned*)Bi_ + bcol*SDW + k0, Bih, Bil);
        } else {
            frag_f32((const float*)Br_ + bcol*SDW + k0, Brh, Brl);
            frag_f32((const float*)Bi_ + bcol*SDW + k0, Bih, Bil);
        }
        short8 nAih = neg8(Aih), nAil = neg8(Ail);
        accR = MFMA(Arh, Brh, accR); accR = MFMA(Arh, Brl, accR); accR = MFMA(Arl, Brh, accR);
        accR = MFMA(nAih, Bih, accR); accR = MFMA(nAih, Bil, accR); accR = MFMA(nAil, Bih, accR);
        if (IMAG) {
            accI = MFMA(Arh, Bih, accI); accI = MFMA(Arh, Bil, accI); accI = MFMA(Arl, Bih, accI);
            accI = MFMA(Aih, Brh, accI); accI = MFMA(Aih, Brl, accI); accI = MFMA(Ail, Brh, accI);
        }
    }
}

// k[h, 64j+i] = Re( g_j . x_i ),  g_j = c^T (dA^64)^j,  x_i = dA^i dB
// Cubic Newton: X1 = I + (dt/2)A; Y = Ab*X1; V = X1*Y; X2 = 3X1 - 3V + VY.
// P = dA = 2*X2 - I folded into m3 epilogue.
// dB = dt/2 (dA b + b): u = dA*b, then x0 = dt/2(u+b), x1 = dt/2(dA u + u).
// Ladder: 9 squarings to dA^512; X-rounds C=2..32 ride s=2..6; G-rounds
// C=1,2,4 ride s=7..9; tail: 3 chained dA^512 G-steps + direct-global K.
__global__ __launch_bounds__(NTH, 4) void ssm_kernel(
    const float* __restrict__ Ag,
    const float* __restrict__ Bg,
    const float* __restrict__ Cg,
    const float* __restrict__ LogDt,
    float* __restrict__ outp)
{
    __shared__ __align__(16) unsigned char lds[122880];
    unsigned* XRr = (unsigned*)(lds +      0);   // packed P row-major (re)
    unsigned* XRi = (unsigned*)(lds +  17408);   // packed P row-major (im)
    unsigned* XTr = (unsigned*)(lds +  34816);   // packed P^T (re)
    unsigned* XTi = (unsigned*)(lds +  52224);   // packed P^T (im)
    float*    Xfr = (float*)(lds +  69632);      // fp32 Xf[v][q] = x_v[q] ; aliases Yt
    float*    Xfi = (float*)(lds +  87040);
    unsigned* U0u = (unsigned*)Xfr;              // Newton Y^T packed (dead before Xf live)
    unsigned* U1u = (unsigned*)Xfi;
    float*    Grf = (float*)(lds + 104448);      // fp32 G[j][q] = g_j[q], 32 rows, stride SDW
    float*    Gif = (float*)(lds + 113152);
    float*    bvr = (float*)(lds + 121856);
    float*    bvi = (float*)(lds + 122112);
    float*    urr = (float*)(lds + 122368);      // u = dA*b scratch
    float*    uri = (float*)(lds + 122624);

    const int t    = threadIdx.x;
    const int lane = t & 63;
    const int wv   = t >> 6;                 // 0..15
    const int ti   = wv >> 2, tj = wv & 3;
    const int fm   = lane & 15, fq = lane >> 4;
    const int h    = blockIdx.x;

    const float dt  = expf(LogDt[h]);
    const float hdt = 0.5f * dt;

    const float2* A2 = (const float2*)(Ag + (size_t)h * NN * NN * 2);
    const float4_t z4 = {0.f, 0.f, 0.f, 0.f};

    // ---- seed P = X1 = I + (dt/2)A packed (both views); load b, c ----
#pragma unroll
    for (int e = 0; e < 4; ++e) {
        int idx = t + e*NTH;
        int i = idx >> 6, j = idx & 63;
        float2 a = A2[idx];
        unsigned pr = pack2((i == j ? 1.0f : 0.0f) + hdt * a.x);
        unsigned pi = pack2(hdt * a.y);
        XRr[i*SDW + j] = pr; XRi[i*SDW + j] = pi;
        XTr[j*SDW + i] = pr; XTi[j*SDW + i] = pi;
    }
    if (t < NN) {
        float2 bv = ((const float2*)Bg)[h*NN + t];
        float2 cv = ((const float2*)Cg)[h*NN + t];
        bvr[t] = bv.x; bvi[t] = bv.y;
        Grf[t] = cv.x; Gif[t] = cv.y;   // g_0 = c
    }
    __syncthreads();

    const int arow = ti*16 + fm;
    const int bcol = tj*16 + fm;

    // ---- m1: Y = Ab*X1 (Ab from global, Bt = XT); write Y^T -> U (b64) ----
    {
        float4_t aR = z4, aI = z4;
#pragma unroll
        for (int ks = 0; ks < 2; ++ks) {
            const int k0 = ks*32 + fq*8;
            unsigned vr[8], vi[8];
#pragma unroll
            for (int j = 0; j < 8; ++j) {
                float2 a = A2[arow*NN + k0 + j];
                vr[j] = __float_as_uint((arow == k0 + j ? 1.0f : 0.0f) - hdt * a.x);
                vi[j] = __float_as_uint(-hdt * a.y);
            }
            short8 Arh, Arl, Aih, Ail, Brh, Brl, Bih, Bil;
            frag_vals(vr, Arh, Arl);
            frag_vals(vi, Aih, Ail);
            frag_packed(XTr + bcol*SDW + k0, Brh, Brl);
            frag_packed(XTi + bcol*SDW + k0, Bih, Bil);
            short8 nAih = neg8(Aih), nAil = neg8(Ail);
            aR = MFMA(Arh, Brh, aR); aR = MFMA(Arh, Brl, aR); aR = MFMA(Arl, Brh, aR);
            aR = MFMA(nAih, Bih, aR); aR = MFMA(nAih, Bil, aR); aR = MFMA(nAil, Bih, aR);
            aI = MFMA(Arh, Bih, aI); aI = MFMA(Arh, Bil, aI); aI = MFMA(Arl, Bih, aI);
            aI = MFMA(Aih, Brh, aI); aI = MFMA(Aih, Brl, aI); aI = MFMA(Ail, Brh, aI);
        }
#pragma unroll
        for (int rp = 0; rp < 2; ++rp) {   // Yt contiguous rows -> b64
            int row0 = ti*16 + fq*4 + rp*2;
            uint2 wr; wr.x = pack2(aR[rp*2]); wr.y = pack2(aR[rp*2+1]);
            uint2 wi; wi.x = pack2(aI[rp*2]); wi.y = pack2(aI[rp*2+1]);
            *(uint2*)(U0u + bcol*SDW + row0) = wr;
            *(uint2*)(U1u + bcol*SDW + row0) = wi;
        }
    }
    __syncthreads();

    // ---- m2: V = X1*Y (A = XR, Bt = U); overwrite XR with V (row-major only) ----
    {
        float4_t aR = z4, aI = z4;
        cmm_tile<true, true, true>(XRr, XRi, U0u, U1u, arow, bcol, fq, aR, aI);
        __syncthreads();   // all X1/Y reads done
#pragma unroll
        for (int r = 0; r < 4; ++r) {
            int row = ti*16 + fq*4 + r;
            XRr[row*SDW + bcol] = pack2(aR[r]);
            XRi[row*SDW + bcol] = pack2(aI[r]);
        }
    }
    __syncthreads();

    // ---- m3: P = dA = 2*(3X1 - 3V + V*Y) - I ; write both views ----
    {
        float4_t aR = z4, aI = z4;
        cmm_tile<true, true, true>(XRr, XRi, U0u, U1u, arow, bcol, fq, aR, aI);
        float p_r[4], p_i[4];
#pragma unroll
        for (int r = 0; r < 4; ++r) {      // pre-barrier elementwise reads
            int row = ti*16 + fq*4 + r;
            float2 a = A2[row*NN + bcol];
            float dd  = (row == bcol ? 1.0f : 0.0f);
            float x1r = dd + hdt * a.x;
            float x1i = hdt * a.y;
            float vvr = unpack2(XRr[row*SDW + bcol]);
            float vvi = unpack2(XRi[row*SDW + bcol]);
            p_r[r] = 2.0f*(3.0f*x1r - 3.0f*vvr + aR[r]) - dd;
            p_i[r] = 2.0f*(3.0f*x1i - 3.0f*vvi + aI[r]);
        }
        __syncthreads();   // all V/Y reads done
        unsigned pr[4], pi[4];
#pragma unroll
        for (int r = 0; r < 4; ++r) {
            int row = ti*16 + fq*4 + r;
            pr[r] = pack2(p_r[r]); pi[r] = pack2(p_i[r]);
            XRr[row*SDW + bcol] = pr[r]; XRi[row*SDW + bcol] = pi[r];
        }
#pragma unroll
        for (int rp = 0; rp < 2; ++rp) {
            int row0 = ti*16 + fq*4 + rp*2;
            uint2 wr; wr.x = pr[rp*2]; wr.y = pr[rp*2+1];
            uint2 wi; wi.x = pi[rp*2]; wi.y = pi[rp*2+1];
            *(uint2*)(XTr + bcol*SDW + row0) = wr;
            *(uint2*)(XTi + bcol*SDW + row0) = wi;
        }
    }
    __syncthreads();
    // P = dA (both views)

    // ---- u = dA*b ----
    {
        int n = t >> 4, part = t & 15;
        float ar = 0.f, ai = 0.f;
#pragma unroll
        for (int qq = 0; qq < 4; ++qq) {
            int k = part + 16*qq;
            float mr = unpack2(XRr[n*SDW + k]), mi = unpack2(XRi[n*SDW + k]);
            ar += mr*bvr[k] - mi*bvi[k];
            ai += mr*bvi[k] + mi*bvr[k];
        }
#pragma unroll
        for (int off = 8; off; off >>= 1) { ar += __shfl_xor(ar, off); ai += __shfl_xor(ai, off); }
        if (part == 0) { urr[n] = ar; uri[n] = ai; }
    }
    __syncthreads();

    // ---- ladder s = 1..9: riders (pre-barrier) + squaring (all 16 waves) ----
    // s=1 rider: x_0 = dt/2(u+b), x_1 = dt/2(dA u + u)  (scalar)
    // s=2..6 rider: X-round C=2^(s-1): Xf[C+r] = Xf[r] . P^T  (Bt = XR)
    // s=7..9 rider: G-round C=2^(s-7): G[C+r] = G[r] . P      (Bt = XT)
    // stale A-rows produce garbage rows >= 2C only, overwritten before use.
#pragma unroll 1
    for (int s = 1; s <= 9; ++s) {
        if (s == 1) {
            int n = t >> 4, part = t & 15;
            float ar = 0.f, ai = 0.f;
#pragma unroll
            for (int qq = 0; qq < 4; ++qq) {
                int k = part + 16*qq;
                float mr = unpack2(XRr[n*SDW + k]), mi = unpack2(XRi[n*SDW + k]);
                ar += mr*urr[k] - mi*uri[k];
                ai += mr*uri[k] + mi*urr[k];
            }
#pragma unroll
            for (int off = 8; off; off >>= 1) { ar += __shfl_xor(ar, off); ai += __shfl_xor(ai, off); }
            if (part == 0) {
                float u_r = urr[n], u_i = uri[n];
                Xfr[n]       = hdt*(u_r + bvr[n]);
                Xfi[n]       = hdt*(u_i + bvi[n]);
                Xfr[SDW + n] = hdt*(ar + u_r);
                Xfi[SDW + n] = hdt*(ai + u_i);
            }
        } else if (s <= 6) {
            const int C = 1 << (s-1);
            const int nT = (s == 6) ? 8 : 4;
            if (wv < nT) {
                const int rt = wv >> 2, ct = wv & 3;
                float4_t aR = z4, aI = z4;
                cmm_tile<false, true, true>(Xfr, Xfi, XRr, XRi, rt*16 + fm, ct*16 + fm, fq, aR, aI);
#pragma unroll
                for (int r = 0; r < 4; ++r) {
                    int row = rt*16 + fq*4 + r;
                    Xfr[(C+row)*SDW + ct*16 + fm] = aR[r];
                    Xfi[(C+row)*SDW + ct*16 + fm] = aI[r];
                }
            }
        } else {
            const int C = 1 << (s-7);     // 1,2,4
            if (wv < 4) {
                float4_t aR = z4, aI = z4;
                cmm_tile<false, true, true>(Grf, Gif, XTr, XTi, fm, wv*16 + fm, fq, aR, aI);
#pragma unroll
                for (int r = 0; r < 4; ++r) {
                    int row = C + fq*4 + r;   // <= 19 < 32, no mask
                    Grf[row*SDW + wv*16 + fm] = aR[r];
                    Gif[row*SDW + wv*16 + fm] = aI[r];
                }
            }
        }
        // squaring (all 16 waves): P <- P*P
        float4_t sR = z4, sI = z4;
        cmm_tile<true, true, true>(XRr, XRi, XTr, XTi, arow, bcol, fq, sR, sI);
        __syncthreads();   // all P reads (riders + frags) complete
        unsigned pr[4], pi[4];
#pragma unroll
        for (int r = 0; r < 4; ++r) {
            int row = ti*16 + fq*4 + r;
            pr[r] = pack2(sR[r]); pi[r] = pack2(sI[r]);
            XRr[row*SDW + bcol] = pr[r]; XRi[row*SDW + bcol] = pi[r];
        }
#pragma unroll
        for (int rp = 0; rp < 2; ++rp) {
            int row0 = ti*16 + fq*4 + rp*2;
            uint2 wr; wr.x = pr[rp*2]; wr.y = pr[rp*2+1];
            uint2 wi; wi.x = pi[rp*2]; wi.y = pi[rp*2+1];
            *(uint2*)(XTr + bcol*SDW + row0) = wr;
            *(uint2*)(XTi + bcol*SDW + row0) = wi;
        }
        __syncthreads();
    }
    // P = dA^512 ; Xf rows 0..63 = x_i ; Gf rows 0..7 = g_0..g_7

    // ---- tail tt = 0..3: chained dA^512 G-steps + K tiles (direct global) ----
    // G rows [8+8tt, 24+8tt) <- A rows [8tt, 8tt+16) (out row 8+ab+m depends
    // only on A row ab+m, so in-interval row overlap is benign).
#pragma unroll 1
    for (int tt = 0; tt < 4; ++tt) {
        if (tt < 3 && wv < 4) {
            const int ab = tt * 8;
            float4_t aR = z4, aI = z4;
            cmm_tile<false, true, true>(Grf, Gif, XTr, XTi, ab + fm, wv*16 + fm, fq, aR, aI);
#pragma unroll
            for (int r = 0; r < 4; ++r) {
                int orow = 8 + ab + fq*4 + r;
                if (orow < 32) {
                    Grf[orow*SDW + wv*16 + fm] = aR[r];
                    Gif[orow*SDW + wv*16 + fm] = aI[r];
                }
            }
        }
        if (wv >= 4 && wv < 8) {           // K rows [8tt, 8tt+8): direct global store
            const int jb = tt * 8;
            float4_t aR = z4, aI = z4;
            cmm_tile<false, false, false>(Grf, Gif, Xfr, Xfi, jb + fm, (wv-4)*16 + fm, fq, aR, aI);
            if (fq < 2) {
                size_t base = (size_t)h * LSEQ;
#pragma unroll
                for (int r = 0; r < 4; ++r)
                    outp[base + (jb + fq*4 + r)*NN + (wv-4)*16 + fm] = aR[r];
            }
        }
        if (tt < 3) __syncthreads();
    }
}

extern "C" void kernel_launch(void* const* d_in, const int* in_sizes, int n_in,
                              void* d_out, int out_size, void* d_ws, size_t ws_size,
                              hipStream_t stream) {
    const float* A  = (const float*)d_in[0];
    const float* B  = (const float*)d_in[1];
    const float* C  = (const float*)d_in[2];
    const float* ld = (const float*)d_in[3];
    float* out = (float*)d_out;
    ssm_kernel<<<dim3(NH), dim3(NTH), 0, stream>>>(A, B, C, ld, out);
}